// Round 3
// baseline (107.499 us; speedup 1.0000x reference)
//
#include <hip/hip_runtime.h>
#include <stdint.h>
#include <math.h>

#define B_    4
#define H_    192
#define W_    192
#define HW    (H_*W_)            // 36864
#define NPIX  (B_*HW)            // 147456
#define C_V   10
#define C_F   64
#define C_D   16
#define C_ALL (C_V+C_F+C_D)      // 90
#define HBINS 32768              // keys always have bit31 set -> real bin = 32768 + hb
#define CAP   2048               // bin-b* list capacity (expected ~150 items)

// ---- workspace layout (bytes) ----
#define OFF_HIST 0u                                   // 4*HBINS*4 = 512 KB (zeroed by k_zero)
#define OFF_KEY  (4u*HBINS*4u)                        // NPIX*4
#define OFF_G    (OFF_KEY + (uint32_t)NPIX*4u)        // NPIX   (packed bytes)
#define OFF_SELX (OFF_G + (uint32_t)NPIX)             // NPIX   (zeroed by k_prep)
#define OFF_HL   (OFF_SELX + (uint32_t)NPIX)          // 4 uints: per-batch sel threshold

__device__ __forceinline__ uint32_t costOf(uint32_t g) {
    return g == 0u ? 10u : (g == 1u ? 5u : 2u);
}

// budget_per_sample = float32(budget / B); usage,c exact ints ->
// usage+c <= bps  <=>  usage+c <= floor(bps)
__device__ __forceinline__ uint32_t budgetInt(const int* bptr) {
    double bps = (double)bptr[0] / (double)B_;
    float f = (float)bps;
    return (uint32_t)floorf(f);
}

// compare-exchange keeping max in x (descending order)
#define CE(x, y) { uint64_t _mn = (x) < (y) ? (x) : (y); \
                   uint64_t _mx = (x) < (y) ? (y) : (x); (x) = _mx; (y) = _mn; }

// K0: zero the histogram (512 KB)
__global__ void k_zero(uint4* __restrict__ hist4) {
    int i = blockIdx.x * blockDim.x + threadIdx.x;   // [0, 32768)
    hist4[i] = make_uint4(0u, 0u, 0u, 0u);
}

// K1: per-pixel best utility / group / sortable key, zero selx, cost histogram.
__global__ void k_prep(const float* __restrict__ util, uint4* __restrict__ key4,
                       uint32_t* __restrict__ g4, uint32_t* __restrict__ selx4,
                       uint32_t* __restrict__ hist) {
    int t = blockIdx.x * blockDim.x + threadIdx.x;   // [0, NPIX/4)
    if (t >= NPIX / 4) return;
    const float4* u4 = (const float4*)util + (size_t)t * 3;
    float4 a = u4[0], b4 = u4[1], c4 = u4[2];
    float u[4][3] = { {a.x, a.y, a.z}, {a.w, b4.x, b4.y},
                      {b4.z, b4.w, c4.x}, {c4.y, c4.z, c4.w} };
    uint32_t kk[4]; uint32_t gpack = 0;
    #pragma unroll
    for (int p = 0; p < 4; ++p) {
        float best = u[p][0]; uint32_t g = 0;
        if (u[p][1] > best) { best = u[p][1]; g = 1; }   // strict > = first max
        if (u[p][2] > best) { best = u[p][2]; g = 2; }
        kk[p] = (best > 0.0f) ? (__float_as_uint(best) | 0x80000000u) : 0u;
        gpack |= g << (8 * p);
    }
    key4[t] = make_uint4(kk[0], kk[1], kk[2], kk[3]);
    g4[t] = gpack;
    selx4[t] = 0u;
    int b = (t * 4) / HW;                     // HW % 4 == 0: group never crosses batch
    #pragma unroll
    for (int p = 0; p < 4; ++p)
        if (kk[p])
            atomicAdd(&hist[(size_t)b * HBINS + ((kk[p] >> 16) & 32767u)],
                      costOf((gpack >> (8 * p)) & 3u));
}

// K2: per batch. Phase A: shfl-scan over hist -> crossing bin b*.
// Phase B: ONE pass over keys: collect bin-b* items + register top-1 cost-5 /
// top-4 cost-2 below b* (tail candidates). Rank-sort + serial greedy replay,
// then exact 5-candidate tail simulation (provably sufficient: r<=9).
__global__ __launch_bounds__(1024) void k_select(const uint32_t* __restrict__ key,
                                                 const uint8_t* __restrict__ g,
                                                 const uint32_t* __restrict__ hist,
                                                 const int* __restrict__ budget_ptr,
                                                 uint8_t* __restrict__ selx,
                                                 uint32_t* __restrict__ hl_out) {
    int b = blockIdx.x;
    int t = threadIdx.x;
    int lane = t & 63, wv = t >> 6;
    uint32_t budget = budgetInt(budget_ptr);

    __shared__ uint64_t e[CAP];
    __shared__ uint64_t s[CAP];
    __shared__ uint32_t wsum[16];
    __shared__ uint64_t red5[16];
    __shared__ uint64_t red2[16][4];
    __shared__ uint64_t cand[5];
    __shared__ uint32_t f_b2, f_usage, sh_n, sh_r;

    if (t == 0) { f_b2 = 0xFFFFFFFFu; f_usage = 0u; sh_n = 0u; }
    __syncthreads();

    // --- Phase A: crossing bin via descending cumsum (shfl wave scan) ---
    const uint32_t* hb = hist + (size_t)b * HBINS;
    int hi = 32767 - 32 * t;                 // chunk t covers bins hi .. hi-31
    uint32_t cs = 0;
    #pragma unroll 4
    for (int j = 0; j < 32; ++j) cs += hb[hi - j];
    uint32_t v = cs;
    #pragma unroll
    for (int off = 1; off < 64; off <<= 1) {
        uint32_t o = __shfl_up(v, off);
        if (lane >= off) v += o;
    }
    if (lane == 63) wsum[wv] = v;
    __syncthreads();
    if (t < 16) {
        uint32_t w = wsum[t];
        #pragma unroll
        for (int off = 1; off < 16; off <<= 1) {
            uint32_t o = __shfl_up(w, off);
            if (t >= off) w += o;
        }
        wsum[t] = w;
    }
    __syncthreads();
    uint32_t incl = v + (wv ? wsum[wv - 1] : 0u);
    uint32_t excl = incl - cs;
    if (excl <= budget && incl > budget) {       // first crossing is in this chunk
        uint32_t cum = excl;
        for (int j = 0; j < 32; ++j) {
            uint32_t hv = hb[hi - j];
            if (cum + hv > budget) { f_b2 = (uint32_t)(hi - j); f_usage = cum; break; }
            cum += hv;
        }
    }
    __syncthreads();
    uint32_t b2 = f_b2;
    if (t == 0) {
        uint32_t hl;
        if (b2 == 0xFFFFFFFFu)           hl = 1u;        // no crossing: all valid selected
        else {
            uint32_t bs = b2 + 32768u;
            hl = (bs >= 65535u) ? 0xFFFFFFFFu : ((bs + 1u) << 16);
        }
        hl_out[b] = hl;
    }
    if (b2 == 0xFFFFFFFFu) return;               // uniform across block

    // --- Phase B: single pass — collect bin b* + tail candidates ---
    // tail item encode: m = (key<<18) | ((65535-pix)<<2) | g   (desc m = walk order)
    const uint32_t* kb = key + (size_t)b * HW;
    const uint8_t*  gb = g   + (size_t)b * HW;
    uint64_t m5 = 0;                              // top-1 cost-5 (g==1) below b*
    uint64_t a0 = 0, a1 = 0, a2 = 0, a3 = 0;      // top-4 cost-2 (g==2) below b*, desc
    for (int i = t; i < HW; i += 1024) {
        uint32_t k = kb[i];
        if (!k) continue;
        uint32_t bin = (k >> 16) & 32767u;
        if (bin == b2) {
            uint32_t idx = atomicAdd(&sh_n, 1u);
            if (idx < CAP)   // asc key: (~k, pix) -> utility desc, pix asc (stable ties)
                e[idx] = ((uint64_t)(~k) << 32) | ((uint64_t)i << 2) | (uint64_t)gb[i];
        } else if (bin < b2) {
            uint32_t gg = gb[i];
            if (gg == 0u) continue;               // cost 10 never fits (r <= 9)
            uint64_t m = ((uint64_t)k << 18) | ((uint64_t)(65535u - (uint32_t)i) << 2)
                       | (uint64_t)gg;
            if (gg == 1u) { if (m > m5) m5 = m; }
            else {
                if (m > a3) {                     // sorted insert, static indices
                    if      (m > a0) { a3 = a2; a2 = a1; a1 = a0; a0 = m; }
                    else if (m > a1) { a3 = a2; a2 = a1; a1 = m; }
                    else if (m > a2) { a3 = a2; a2 = m; }
                    else             { a3 = m; }
                }
            }
        }
    }
    // wave-level reduce: max for m5; bitonic top-4 merge for a0..a3
    #pragma unroll
    for (int off = 32; off; off >>= 1) {
        uint64_t o5 = __shfl_down(m5, off);
        if (o5 > m5) m5 = o5;
        uint64_t b0 = __shfl_down(a0, off), b1 = __shfl_down(a1, off),
                 b2_ = __shfl_down(a2, off), b3 = __shfl_down(a3, off);
        CE(a0, b3); CE(a1, b2_); CE(a2, b1); CE(a3, b0);  // bitonic split (top half)
        CE(a0, a2); CE(a1, a3); CE(a0, a1); CE(a2, a3);   // sort bitonic 4 desc
    }
    if (lane == 0) {
        red5[wv] = m5;
        red2[wv][0] = a0; red2[wv][1] = a1; red2[wv][2] = a2; red2[wv][3] = a3;
    }
    __syncthreads();
    int n = (int)(sh_n < (uint32_t)CAP ? sh_n : (uint32_t)CAP);

    // --- rank sort of bin-b* items (composite keys distinct) ---
    for (int i = t; i < n; i += 1024) {
        uint64_t ei = e[i];
        int rk = 0;
        for (int j = 0; j < n; ++j) rk += (e[j] < ei);
        s[rk] = ei;
    }
    __syncthreads();

    // --- serial greedy in bin b*, then exact tail simulation ---
    if (t == 0) {
        uint32_t usage = f_usage;
        uint8_t* sx = selx + (size_t)b * HW;
        for (int i = 0; i < n; ++i) {
            uint64_t ei = s[i];
            uint32_t c = costOf((uint32_t)(ei & 3u));
            if (usage + c <= budget) { usage += c; sx[(ei >> 2) & 0xFFFFu] = 1; }
        }
        // global top candidates from the 16 wave results
        uint64_t g5 = 0, t0 = 0, t1 = 0, t2 = 0, t3 = 0;
        for (int wq = 0; wq < 16; ++wq) {
            if (red5[wq] > g5) g5 = red5[wq];
            #pragma unroll
            for (int q = 0; q < 4; ++q) {
                uint64_t m = red2[wq][q];
                if (m > t3) {
                    if      (m > t0) { t3 = t2; t2 = t1; t1 = t0; t0 = m; }
                    else if (m > t1) { t3 = t2; t2 = t1; t1 = m; }
                    else if (m > t2) { t3 = t2; t2 = m; }
                    else             { t3 = m; }
                }
            }
        }
        cand[0] = g5; cand[1] = t0; cand[2] = t1; cand[3] = t2; cand[4] = t3;
        // insertion sort 5 desc (LDS, tiny)
        for (int i = 1; i < 5; ++i) {
            uint64_t x = cand[i]; int j = i;
            while (j > 0 && cand[j - 1] < x) { cand[j] = cand[j - 1]; --j; }
            cand[j] = x;
        }
        // walk in desc order: exact replay of the reference greedy below bin b*
        uint32_t r = budget - usage;             // provably <= 9
        for (int i = 0; i < 5; ++i) {
            uint64_t m = cand[i];
            if (!m) break;
            uint32_t c = costOf((uint32_t)(m & 3u));
            if (c <= r) {
                r -= c;
                uint32_t pix = 65535u - (uint32_t)((m >> 2) & 0xFFFFu);
                sx[pix] = 1;
            }
        }
        sh_r = r; (void)sh_r;
    }
}

// K3: masked sparse BEV + sel_idx output (c==0 blocks), float4-vectorized.
__global__ void k_sparse(const float* __restrict__ collab, const uint4* __restrict__ key4,
                         const uint32_t* __restrict__ g4, const uint32_t* __restrict__ selx4,
                         const uint32_t* __restrict__ hl_arr,
                         float* __restrict__ out, float* __restrict__ selOut) {
    int tid = blockIdx.x * blockDim.x + threadIdx.x;   // [0, HW/4)
    int c = blockIdx.y, b = blockIdx.z;
    int cls = (c < C_V) ? 0 : ((c < C_V + C_F) ? 1 : 2);
    uint32_t hl = hl_arr[b];                           // >= 1 always
    size_t p4 = (size_t)b * (HW / 4) + (size_t)tid;
    uint4 kk = key4[p4];
    uint32_t gg = g4[p4];
    uint32_t sx = selx4[p4];
    int sc[4];
    uint32_t kv[4] = { kk.x, kk.y, kk.z, kk.w };
    #pragma unroll
    for (int p = 0; p < 4; ++p) {
        bool se = (kv[p] >= hl) || (((sx >> (8 * p)) & 0xFFu) != 0u);
        sc[p] = se ? (int)((gg >> (8 * p)) & 3u) : -1;
    }
    size_t co = ((size_t)(b * C_ALL + c)) * HW + (size_t)tid * 4;
    float4 v = *(const float4*)(collab + co);
    float4 o;
    o.x = (sc[0] == cls) ? v.x : 0.0f;
    o.y = (sc[1] == cls) ? v.y : 0.0f;
    o.z = (sc[2] == cls) ? v.z : 0.0f;
    o.w = (sc[3] == cls) ? v.w : 0.0f;
    *(float4*)(out + co) = o;
    if (c == 0) {
        float4 sf = make_float4((float)sc[0], (float)sc[1], (float)sc[2], (float)sc[3]);
        ((float4*)selOut)[p4] = sf;
    }
}

extern "C" void kernel_launch(void* const* d_in, const int* in_sizes, int n_in,
                              void* d_out, int out_size, void* d_ws, size_t ws_size,
                              hipStream_t stream) {
    (void)in_sizes; (void)n_in; (void)out_size; (void)ws_size;
    const float* collab = (const float*)d_in[0];
    const float* util   = (const float*)d_in[1];
    const int*   budget = (const int*)d_in[2];

    uint8_t*  ws   = (uint8_t*)d_ws;
    uint32_t* hist = (uint32_t*)(ws + OFF_HIST);
    uint32_t* key  = (uint32_t*)(ws + OFF_KEY);
    uint8_t*  g    = ws + OFF_G;
    uint8_t*  selx = ws + OFF_SELX;
    uint32_t* hl   = (uint32_t*)(ws + OFF_HL);

    float* outSparse = (float*)d_out;
    float* outSel    = outSparse + (size_t)B_ * C_ALL * HW;

    k_zero  <<<(4 * HBINS / 4) / 256, 256, 0, stream>>>((uint4*)hist);
    k_prep  <<<(NPIX / 4 + 255) / 256, 256, 0, stream>>>(util, (uint4*)key,
                                                         (uint32_t*)g, (uint32_t*)selx, hist);
    k_select<<<B_, 1024, 0, stream>>>(key, g, hist, budget, selx, hl);
    dim3 grid3(HW / 4 / 256, C_ALL, B_);
    k_sparse<<<grid3, 256, 0, stream>>>(collab, (const uint4*)key, (const uint32_t*)g,
                                        (const uint32_t*)selx, hl, outSparse, outSel);
}